// Round 6
// baseline (370.589 us; speedup 1.0000x reference)
//
#include <hip/hip_runtime.h>
#include <math.h>

#define N_ROWS 65536
#define KCODES 8192
#define DIM 64
#define MARGIN_S 0.2f            // scaled by 4096 (z,w each scaled x64); unscaled 4.9e-5
#define KSPLIT 4
#define KPER (KCODES / KSPLIT)   // 2048
#define NROUNDS (KPER / 64)      // 32
#define LIST_CAP 32768

// ws layout (floats) — proven footprint (606209 floats)
#define WS_WSQ   0          // 8192
#define WS_IDX   8192       // 65536 ints
#define WS_BINS  73728      // 8192
#define WS_ESUM  81920      // 524288  (wT during fallback; zeroed by merge2)
#define WS_LOSS  606208     // 1

// d_out scratch map (all regions rewritten by later kernels):
//   zn fp32:   out[0 .. 4194304)        (z_q region; stats overwrites)
//   count:     out[4194304]             (loss slot; finalize overwrites)
//   list:      out[4194305 .. 4259841)  (idx region; stats overwrites)
//   whl fp16:  out[4268032 .. 4792320)  (cs-last + ea region; finalize overwrites)
//   pm1/fbmin: out[4792321 .. 5054465)  (w region; finalize overwrites)
//   pack/fbk:  out[5054465 .. 5316609)

typedef _Float16 half8 __attribute__((ext_vector_type(8)));
typedef float f32x4 __attribute__((ext_vector_type(4)));

#define MFMA_F16(A, B, C) __builtin_amdgcn_mfma_f32_16x16x32_f16(A, B, C, 0, 0, 0)

__device__ __forceinline__ float b2f(unsigned short h) {
    return __uint_as_float(((unsigned)h) << 16);
}
__device__ __forceinline__ unsigned short f2h(float f, float* back) {
    union { _Float16 h; unsigned short u; } cv;
    cv.h = (_Float16)f;            // v_cvt_f16_f32 (RTNE)
    *back = (float)cv.h;
    return cv.u;
}
__device__ __forceinline__ void gload16(const unsigned short* g, unsigned short* l) {
    __builtin_amdgcn_global_load_lds(
        (const __attribute__((address_space(1))) unsigned int*)g,
        (__attribute__((address_space(3))) unsigned int*)l, 16, 0, 0);
}

// ---------------- kernel A0: normalize z once (+ zero count/loss) ----------------
__global__ void prep_z_kernel(const float* __restrict__ z, float* __restrict__ zn,
                              int* __restrict__ countp, float* __restrict__ loss) {
    if (blockIdx.x == 0 && threadIdx.x == 0) { *countp = 0; *loss = 0.f; }
    const int lane = threadIdx.x & 63;
    const int wv = threadIdx.x >> 6;
    const int base = blockIdx.x * 64;
    for (int i = 0; i < 16; ++i) {
        int row = base + i * 4 + wv;
        float v = z[(size_t)row * DIM + lane];
        float s = v * v;
        #pragma unroll
        for (int off = 32; off > 0; off >>= 1) s += __shfl_xor(s, off);
        zn[(size_t)row * DIM + lane] = v / fmaxf(sqrtf(s), 1e-12f);
    }
}

// ---------------- kernel A1: wsq + fp16 hi/lo split (x64) + transpose + zero bins ----------------
__global__ void prep_w_kernel(const float* __restrict__ w, float* __restrict__ wsq,
                              unsigned short* __restrict__ whl, float* __restrict__ wT,
                              float* __restrict__ bins) {
    __shared__ float tile[64 * 65];
    const int t = threadIdx.x;
    const int lane = t & 63;
    const int wv = t >> 6;
    const int c0 = blockIdx.x * 64;
    if (t < 64) bins[c0 + t] = 0.f;
    for (int cc = 0; cc < 16; ++cc) {
        int c = wv * 16 + cc;
        float v = w[(size_t)(c0 + c) * DIM + lane];
        tile[c * 65 + lane] = v;
        float s = v * v;
        #pragma unroll
        for (int off = 32; off > 0; off >>= 1) s += __shfl_xor(s, off);
        if (lane == 0) wsq[c0 + c] = s;
        float vs = v * 64.0f;
        float hf;
        unsigned short hb = f2h(vs, &hf);
        float dummy;
        unsigned short lb = f2h(vs - hf, &dummy);
        whl[(size_t)(c0 + c) * 128 + lane] = hb;
        whl[(size_t)(c0 + c) * 128 + 64 + lane] = lb;
    }
    __syncthreads();
    #pragma unroll
    for (int i = 0; i < 16; ++i) {
        int idx = i * 256 + t;
        int d = idx >> 6, c = idx & 63;
        wT[(size_t)d * KCODES + c0 + c] = tile[c * 65 + d];
    }
}

// ---------------- kernel B: K-split fp16 MFMA argmax-dot, 512 thr / 8 waves ----------------
// grid 2048 = 512 rowblocks(128 rows) x 4 k-quarters; wave owns 16 rows; 4 blocks/CU.
__launch_bounds__(512, 8)
__global__ void argmin_mfma_kernel(const float* __restrict__ zn,
                                   const unsigned short* __restrict__ whl,
                                   float* __restrict__ pm1,
                                   unsigned int* __restrict__ pack) {
    __shared__ unsigned short smem[16384];   // 2 x 16 KB B-tile buffers

    const int tid = threadIdx.x;
    const int lane = tid & 63;
    const int wv = tid >> 6;           // 0..7
    const int n_a = lane & 15;
    const int quad = lane >> 4;
    const int rowblk = blockIdx.x >> 2;
    const int kq = blockIdx.x & 3;
    const int kbase = kq * KPER;

    // tile = 64 codes x 128 fp16 = 16 KB = 1024 16B-segments; thread stages 2.
    #define ISSUE_TILE(r, bdst)                                                  \
        {                                                                        \
            const size_t cg0 = (size_t)(kbase + (r) * 64);                       \
            _Pragma("unroll")                                                    \
            for (int i = 0; i < 2; ++i) {                                        \
                int slot = i * 512 + tid;                                        \
                int cl = slot >> 4;                                              \
                int jg = (slot & 15) ^ (cl & 15);                                \
                gload16(whl + (cg0 + cl) * 128 + jg * 8,                         \
                        (bdst) + i * 4096 + wv * 512);                           \
            }                                                                    \
        }

    ISSUE_TILE(0, smem);

    // A fragments: load zn, scale x64, split to fp16 hi/lo in registers
    half8 a_h[2], a_l[2];
    {
        int row = rowblk * 128 + wv * 16 + n_a;
        #pragma unroll
        for (int ks = 0; ks < 2; ++ks) {
            const float* p = zn + (size_t)row * DIM + ks * 32 + quad * 8;
            float4 f0 = *(const float4*)p;
            float4 f1 = *(const float4*)(p + 4);
            float f[8] = {f0.x, f0.y, f0.z, f0.w, f1.x, f1.y, f1.z, f1.w};
            half8 vh, vl;
            #pragma unroll
            for (int j = 0; j < 8; ++j) {
                float vs = f[j] * 64.0f;
                _Float16 h = (_Float16)vs;
                vh[j] = h;
                vl[j] = (_Float16)(vs - (float)h);
            }
            a_h[ks] = vh; a_l[ks] = vl;
        }
    }

    float m1v[4], m2v[4];
    int kkv[4];
    #pragma unroll
    for (int i = 0; i < 4; ++i) { m1v[i] = -3.4e38f; m2v[i] = -3.4e38f; kkv[i] = 0; }

    __syncthreads();

    for (int r = 0; r < NROUNDS; ++r) {
        unsigned short* bc = smem + (r & 1) * 8192;
        if (r + 1 < NROUNDS) ISSUE_TILE(r + 1, smem + ((r + 1) & 1) * 8192);

        #pragma unroll
        for (int nt = 0; nt < 4; ++nt) {
            const int cl = nt * 16 + n_a;
            const unsigned short* bp = bc + cl * 128;
            half8 bh0 = *(const half8*)(bp + ((quad) ^ n_a) * 8);
            half8 bh1 = *(const half8*)(bp + ((4 + quad) ^ n_a) * 8);
            half8 bl0 = *(const half8*)(bp + ((8 + quad) ^ n_a) * 8);
            half8 bl1 = *(const half8*)(bp + ((12 + quad) ^ n_a) * 8);
            f32x4 a = {0.f, 0.f, 0.f, 0.f};
            a = MFMA_F16(a_h[0], bh0, a);
            a = MFMA_F16(a_h[1], bh1, a);
            a = MFMA_F16(a_l[0], bh0, a);
            a = MFMA_F16(a_l[1], bh1, a);
            a = MFMA_F16(a_h[0], bl0, a);
            a = MFMA_F16(a_h[1], bl1, a);
            const int c = kbase + r * 64 + nt * 16 + n_a;
            #pragma unroll
            for (int i = 0; i < 4; ++i) {
                float v = a[i];
                m2v[i] = __builtin_amdgcn_fmed3f(v, m1v[i], m2v[i]);
                bool gt = v > m1v[i];
                kkv[i] = gt ? c : kkv[i];
                m1v[i] = fmaxf(m1v[i], v);
            }
        }
        __syncthreads();
    }

    // reduce top-2 across 16 col-lanes per row; write compressed partials
    #pragma unroll
    for (int i = 0; i < 4; ++i) {
        float v1 = m1v[i], v2 = m2v[i];
        int k = kkv[i];
        #pragma unroll
        for (int off = 1; off < 16; off <<= 1) {
            float o1 = __shfl_xor(v1, off);
            float o2 = __shfl_xor(v2, off);
            int ok = __shfl_xor(k, off);
            float lo = fminf(v1, o1);
            v2 = fmaxf(fmaxf(v2, o2), lo);
            bool take = (o1 > v1) || (o1 == v1 && ok < k);
            k = take ? ok : k;
            v1 = fmaxf(v1, o1);
        }
        if (n_a == 0) {
            int row_g = rowblk * 128 + wv * 16 + quad * 4 + i;
            float gap = v1 - v2;
            unsigned gb = __float_as_uint(gap) >> 16;   // bf16-truncate: conservative
            pm1[row_g * 4 + kq] = v1;
            pack[row_g * 4 + kq] = (gb << 16) | (unsigned)k;
        }
    }
    #undef ISSUE_TILE
}

// ---------------- kernel C: merge 4 K-partials per row, flag close rows ----------------
__global__ void merge_kernel(const float* __restrict__ pm1, const unsigned int* __restrict__ pack,
                             int* __restrict__ idx_ws,
                             int* __restrict__ countp, int* __restrict__ list) {
    int row = blockIdx.x * blockDim.x + threadIdx.x;
    if (row >= N_ROWS) return;
    float v1 = -3.4e38f, v2 = -3.4e38f;
    int k1 = 0x7fffffff;
    #pragma unroll
    for (int kq = 0; kq < KSPLIT; ++kq) {
        float a1 = pm1[row * 4 + kq];
        unsigned p = pack[row * 4 + kq];
        int ak = (int)(p & 0xFFFFu);
        float a2 = a1 - b2f((unsigned short)(p >> 16));
        if (a1 > v1) { v2 = fmaxf(v1, a2); v1 = a1; k1 = ak; }
        else { v2 = fmaxf(v2, a1); if (a1 == v1 && ak < k1) k1 = ak; }
    }
    idx_ws[row] = k1;
    if (v1 - v2 < MARGIN_S) {
        int pos = atomicAdd(countp, 1);
        if (pos < LIST_CAP) list[pos] = row;
    }
}

// ---------------- kernel D: exact fp32 re-rank, parallel over (slot x code-chunk) ----------------
__launch_bounds__(256, 4)
__global__ void fallback_kernel(const float* __restrict__ zn, const float* __restrict__ wT,
                                const float* __restrict__ wsq,
                                const int* __restrict__ countp, const int* __restrict__ list,
                                float* __restrict__ fbmin, int* __restrict__ fbk) {
    __shared__ float zr_s[64];
    __shared__ float zsq_s;
    __shared__ float wmin_s[4];
    __shared__ int wk_s[4];

    const int t = threadIdx.x;
    const int lane = t & 63;
    const int wv = t >> 6;
    const int count = min(*countp, LIST_CAP);
    const int nunits = count * 8;

    for (int bi = blockIdx.x; bi < nunits; bi += gridDim.x) {
        const int slot = bi >> 3;
        const int chunk = bi & 7;
        const int row = list[slot];

        __syncthreads();
        if (t < 64) {
            float v = zn[(size_t)row * DIM + t];
            zr_s[t] = v;
            float q = v * v;
            #pragma unroll
            for (int off = 32; off > 0; off >>= 1) q += __shfl_xor(q, off);
            if (t == 0) zsq_s = q;
        }
        __syncthreads();

        float acc0 = 0.f, acc1 = 0.f, acc2 = 0.f, acc3 = 0.f;
        const float* wTp = wT + chunk * 1024 + t;
        #pragma unroll 8
        for (int d = 0; d < 64; ++d) {
            float zd = zr_s[d];
            const float* p = wTp + (size_t)d * KCODES;
            acc0 = fmaf(zd, p[0], acc0);
            acc1 = fmaf(zd, p[256], acc1);
            acc2 = fmaf(zd, p[512], acc2);
            acc3 = fmaf(zd, p[768], acc3);
        }

        float zq2 = zsq_s;
        float dmin = 3.4e38f;
        int kmin = 0;
        float a[4] = {acc0, acc1, acc2, acc3};
        #pragma unroll
        for (int j = 0; j < 4; ++j) {
            int c = chunk * 1024 + j * 256 + t;
            float dist = (zq2 - 2.0f * a[j]) + wsq[c];
            if (dist < dmin) { dmin = dist; kmin = c; }
        }
        #pragma unroll
        for (int off = 1; off < 64; off <<= 1) {
            float d2 = __shfl_xor(dmin, off);
            int k2 = __shfl_xor(kmin, off);
            if (d2 < dmin || (d2 == dmin && k2 < kmin)) { dmin = d2; kmin = k2; }
        }
        if (lane == 0) { wmin_s[wv] = dmin; wk_s[wv] = kmin; }
        __syncthreads();
        if (t == 0) {
            float dv = wmin_s[0]; int kv = wk_s[0];
            #pragma unroll
            for (int i = 1; i < 4; ++i) {
                float d2 = wmin_s[i]; int k2 = wk_s[i];
                if (d2 < dv || (d2 == dv && k2 < kv)) { dv = d2; kv = k2; }
            }
            fbmin[bi] = dv;
            fbk[bi] = kv;
        }
    }
}

// ---------------- kernel D2: merge 8 chunk partials per flagged row (+ zero esum) ----------------
__global__ void merge2_kernel(const float* __restrict__ fbmin, const int* __restrict__ fbk,
                              const int* __restrict__ countp, const int* __restrict__ list,
                              int* __restrict__ idx_ws, float* __restrict__ esum) {
    int gid = blockIdx.x * blockDim.x + threadIdx.x;
    // zero esum (wT region is dead now): 65536 threads x 8 floats
    float4 zero4 = {0.f, 0.f, 0.f, 0.f};
    *(float4*)(esum + (size_t)gid * 8) = zero4;
    *(float4*)(esum + (size_t)gid * 8 + 4) = zero4;
    int count = min(*countp, LIST_CAP);
    if (gid >= count) return;
    float dv = 3.4e38f;
    int kv = 0;
    #pragma unroll
    for (int c = 0; c < 8; ++c) {
        float d2 = fbmin[gid * 8 + c];
        int k2 = fbk[gid * 8 + c];
        if (d2 < dv || (d2 == dv && k2 < kv)) { dv = d2; kv = k2; }
    }
    idx_ws[list[gid]] = kv;
}

// ---------------- kernel E: gather z_q (over zn in-place), idx out, loss, EMA scatter ----------------
__global__ void stats_kernel(float* __restrict__ zq,              // holds zn on entry
                             const float* __restrict__ w,
                             const int* __restrict__ idx_ws,
                             float* __restrict__ idx_out,
                             float* __restrict__ bins,
                             float* __restrict__ esum,
                             float* __restrict__ loss_acc) {
    const int lane = threadIdx.x & 63;
    const int wv = threadIdx.x >> 6;
    const int gw = blockIdx.x * 4 + wv;
    const int nw = gridDim.x * 4;
    float lsum = 0.f;
    for (int row = gw; row < N_ROWS; row += nw) {
        float znv = zq[(size_t)row * DIM + lane];
        int k = idx_ws[row];
        float wq = w[(size_t)k * DIM + lane];
        zq[(size_t)row * DIM + lane] = wq;
        if (lane == 0) idx_out[row] = (float)k;
        float diff = wq - znv;
        lsum += diff * diff;
        atomicAdd(&esum[(size_t)k * DIM + lane], znv);
        if (lane == 0) atomicAdd(&bins[k], 1.0f);
    }
    __shared__ float red[256];
    red[threadIdx.x] = lsum;
    __syncthreads();
    for (int s = 128; s > 0; s >>= 1) {
        if (threadIdx.x < s) red[threadIdx.x] += red[threadIdx.x + s];
        __syncthreads();
    }
    if (threadIdx.x == 0) atomicAdd(loss_acc, red[0]);
}

// ---------------- kernel F: per-code EMA finalize + loss scalar ----------------
__global__ void finalize_kernel(const float* __restrict__ w,
                                const float* __restrict__ cs,
                                const float* __restrict__ ea,
                                const float* __restrict__ bins,
                                const float* __restrict__ esum,
                                const float* __restrict__ loss_acc,
                                float* __restrict__ out_cs,
                                float* __restrict__ out_ea,
                                float* __restrict__ out_w,
                                float* __restrict__ out_loss) {
    const int gid = blockIdx.x * blockDim.x + threadIdx.x;
    if (gid == 0) out_loss[0] = 0.25f * loss_acc[0] / 4194304.0f;
    const int k = gid >> 6;
    const int lane = threadIdx.x & 63;
    if (k >= KCODES) return;
    float b = bins[k];
    if (lane == 0) out_cs[k] = cs[k] * 0.99f + 0.01f * b;
    size_t off = (size_t)k * DIM + lane;
    float es = esum[off];
    out_ea[off] = ea[off] * 0.99f + 0.01f * es;
    float wv = w[off];
    float bc = (b == 0.0f) ? 1.0f : b;
    float t = es / bc;
    float s = t * t;
    #pragma unroll
    for (int o = 32; o > 0; o >>= 1) s += __shfl_xor(s, o);
    float en = t / fmaxf(sqrtf(s), 1e-12f);
    if (b == 0.0f) en = wv;
    float nw = wv * 0.99f + 0.01f * en;
    float s2 = nw * nw;
    #pragma unroll
    for (int o = 32; o > 0; o >>= 1) s2 += __shfl_xor(s2, o);
    out_w[off] = nw / fmaxf(sqrtf(s2), 1e-12f);
}

extern "C" void kernel_launch(void* const* d_in, const int* in_sizes, int n_in,
                              void* d_out, int out_size, void* d_ws, size_t ws_size,
                              hipStream_t stream) {
    const float* z  = (const float*)d_in[0];
    const float* w  = (const float*)d_in[1];
    const float* cs = (const float*)d_in[2];
    const float* ea = (const float*)d_in[3];

    float* out = (float*)d_out;
    float* out_zq   = out;                 // 4194304  (zn scratch)
    float* out_loss = out + 4194304;       // 1        (count scratch)
    float* out_idx  = out + 4194305;       // 65536    (list scratch)
    float* out_cs   = out + 4259841;       // 8192
    float* out_ea   = out + 4268033;       // 524288
    float* out_w    = out + 4792321;       // 524288   (pm1/fbmin + pack/fbk scratch)

    float*          zn     = out_zq;
    int*            countp = (int*)(out + 4194304);
    int*            list   = (int*)(out + 4194305);
    unsigned short* whl    = (unsigned short*)(out + 4268032);   // 16B-aligned
    float*          pm1    = out + 4792321;
    unsigned int*   pack   = (unsigned int*)(out + 5054465);
    float*          fbmin  = pm1;
    int*            fbk    = (int*)pack;

    float* ws = (float*)d_ws;
    float* wsq  = ws + WS_WSQ;
    int*   idxb = (int*)(ws + WS_IDX);
    float* bins = ws + WS_BINS;
    float* esum = ws + WS_ESUM;
    float* wT   = ws + WS_ESUM;            // wT lives here until merge2 zeroes it
    float* loss = ws + WS_LOSS;

    prep_z_kernel<<<N_ROWS / 64, 256, 0, stream>>>(z, zn, countp, loss);
    prep_w_kernel<<<KCODES / 64, 256, 0, stream>>>(w, wsq, whl, wT, bins);
    argmin_mfma_kernel<<<(N_ROWS / 128) * KSPLIT, 512, 0, stream>>>(zn, whl, pm1, pack);
    merge_kernel<<<N_ROWS / 256, 256, 0, stream>>>(pm1, pack, idxb, countp, list);
    fallback_kernel<<<2048, 256, 0, stream>>>(zn, wT, wsq, countp, list, fbmin, fbk);
    merge2_kernel<<<256, 256, 0, stream>>>(fbmin, fbk, countp, list, idxb, esum);
    stats_kernel<<<512, 256, 0, stream>>>(out_zq, w, idxb, out_idx, bins, esum, loss);
    finalize_kernel<<<KCODES * 64 / 256, 256, 0, stream>>>(w, cs, ea, bins, esum, loss,
                                                           out_cs, out_ea, out_w, out_loss);
}

// Round 7
// 354.550 us; speedup vs baseline: 1.0452x; 1.0452x over previous
//
#include <hip/hip_runtime.h>
#include <math.h>

#define N_ROWS 65536
#define KCODES 8192
#define DIM 64
#define MARGIN_S 0.2f            // scaled by 4096 (z,w each scaled x64); unscaled 4.9e-5
#define KSPLIT 4
#define KPER (KCODES / KSPLIT)   // 2048
#define NROUNDS (KPER / 64)      // 32
#define LIST_CAP 32768

// ws layout (floats) — proven footprint (606209 floats)
#define WS_WSQ   0          // 8192
#define WS_IDX   8192       // 65536 ints
#define WS_BINS  73728      // 8192
#define WS_ESUM  81920      // 524288  (wT during fallback; zeroed by merge2)
#define WS_LOSS  606208     // 1

// d_out scratch map (all regions rewritten by later kernels):
//   zn fp32:    out[0 .. 4194304)        (z_q region; stats overwrites)
//   count:      out[4194304]             (loss slot; finalize overwrites)
//   list:       out[4194305 .. 4259841)  (idx region; stats overwrites)
//   wfrag fp16: out[4268032 .. 4792320)  (cs-last + ea region; finalize overwrites)
//   pm1/fbmin:  out[4792321 .. 5054465)  (w region; finalize overwrites)
//   pack/fbk:   out[5054465 .. 5316609)

typedef _Float16 half8 __attribute__((ext_vector_type(8)));
typedef float f32x4 __attribute__((ext_vector_type(4)));

#define MFMA_F16(A, B, C) __builtin_amdgcn_mfma_f32_16x16x32_f16(A, B, C, 0, 0, 0)

__device__ __forceinline__ float b2f(unsigned short h) {
    return __uint_as_float(((unsigned)h) << 16);
}

// ---------------- kernel A0: normalize z once (+ zero count/loss) ----------------
__global__ void prep_z_kernel(const float* __restrict__ z, float* __restrict__ zn,
                              int* __restrict__ countp, float* __restrict__ loss) {
    if (blockIdx.x == 0 && threadIdx.x == 0) { *countp = 0; *loss = 0.f; }
    const int lane = threadIdx.x & 63;
    const int wv = threadIdx.x >> 6;
    const int base = blockIdx.x * 64;
    for (int i = 0; i < 16; ++i) {
        int row = base + i * 4 + wv;
        float v = z[(size_t)row * DIM + lane];
        float s = v * v;
        #pragma unroll
        for (int off = 32; off > 0; off >>= 1) s += __shfl_xor(s, off);
        zn[(size_t)row * DIM + lane] = v / fmaxf(sqrtf(s), 1e-12f);
    }
}

// ---------------- kernel A1: wsq + fp16 hi/lo FRAGMENT-LAYOUT split + transpose + zero bins --
// wfrag layout (halves): [tile(512)][seg(4)][lane(64)][8]
//   lane=(n_a,quad); seg: 0=hi ks0, 1=hi ks1, 2=lo ks0, 3=lo ks1
//   element j: code = tile*16+n_a, dim = (seg&1)*32 + quad*8 + j, value scaled x64
__global__ void prep_w_kernel(const float* __restrict__ w, float* __restrict__ wsq,
                              unsigned short* __restrict__ wfrag, float* __restrict__ wT,
                              float* __restrict__ bins) {
    __shared__ float tile[64 * 65];
    const int t = threadIdx.x;
    const int lane = t & 63;
    const int wvv = t >> 6;
    const int c0 = blockIdx.x * 64;
    if (t < 64) bins[c0 + t] = 0.f;
    for (int cc = 0; cc < 16; ++cc) {
        int c = wvv * 16 + cc;
        float v = w[(size_t)(c0 + c) * DIM + lane];
        tile[c * 65 + lane] = v;
        float s = v * v;
        #pragma unroll
        for (int off = 32; off > 0; off >>= 1) s += __shfl_xor(s, off);
        if (lane == 0) wsq[c0 + c] = s;
    }
    __syncthreads();
    // fragment-layout stores: 1024 units = tile_local(4) x seg(4) x lane(64)
    #pragma unroll
    for (int i = 0; i < 4; ++i) {
        int u = i * 256 + t;
        int tl = u >> 8;
        int seg = (u >> 6) & 3;
        int l = u & 63;
        int na = l & 15, qd = l >> 4;
        int cl = tl * 16 + na;
        int dimb = (seg & 1) * 32 + qd * 8;
        int part = seg >> 1;
        half8 out8;
        #pragma unroll
        for (int j = 0; j < 8; ++j) {
            float vs = tile[cl * 65 + dimb + j] * 64.0f;
            _Float16 h = (_Float16)vs;
            out8[j] = part ? (_Float16)(vs - (float)h) : h;
        }
        *(half8*)(wfrag + ((size_t)(blockIdx.x * 4 + tl) * 2048 + seg * 512 + l * 8)) = out8;
    }
    // transpose for fallback
    #pragma unroll
    for (int i = 0; i < 16; ++i) {
        int idx = i * 256 + t;
        int d = idx >> 6, c = idx & 63;
        wT[(size_t)d * KCODES + c0 + c] = tile[c * 65 + d];
    }
}

// ---------------- kernel B: register-direct fp16 MFMA argmax-dot — no LDS, no barriers ----
// grid 2048 = 512 rowblocks(128 rows) x 4 kq; 4 waves x 32 rows (mt=2); 4 blocks/CU.
__launch_bounds__(256, 4)
__global__ void argmin_mfma_kernel(const float* __restrict__ zn,
                                   const unsigned short* __restrict__ wfrag,
                                   float* __restrict__ pm1,
                                   unsigned int* __restrict__ pack) {
    const int tid = threadIdx.x;
    const int lane = tid & 63;
    const int wv = tid >> 6;
    const int n_a = lane & 15;
    const int quad = lane >> 4;
    const int rowblk = blockIdx.x >> 2;
    const int kq = blockIdx.x & 3;

    // A fragments: load zn, scale x64, split to fp16 hi/lo in registers (mt=2)
    half8 a_h[2][2], a_l[2][2];
    #pragma unroll
    for (int mt = 0; mt < 2; ++mt) {
        int row = rowblk * 128 + wv * 32 + mt * 16 + n_a;
        #pragma unroll
        for (int ks = 0; ks < 2; ++ks) {
            const float* p = zn + (size_t)row * DIM + ks * 32 + quad * 8;
            float4 f0 = *(const float4*)p;
            float4 f1 = *(const float4*)(p + 4);
            float f[8] = {f0.x, f0.y, f0.z, f0.w, f1.x, f1.y, f1.z, f1.w};
            half8 vh, vl;
            #pragma unroll
            for (int j = 0; j < 8; ++j) {
                float vs = f[j] * 64.0f;
                _Float16 h = (_Float16)vs;
                vh[j] = h;
                vl[j] = (_Float16)(vs - (float)h);
            }
            a_h[mt][ks] = vh; a_l[mt][ks] = vl;
        }
    }

    float m1v[2][4], m2v[2][4];
    int kkv[2][4];
    #pragma unroll
    for (int mt = 0; mt < 2; ++mt)
        #pragma unroll
        for (int i = 0; i < 4; ++i) { m1v[mt][i] = -3.4e38f; m2v[mt][i] = -3.4e38f; kkv[mt][i] = 0; }

    // B fragments straight from global (L1/L2-resident stream, lane-coalesced 16B)
    const unsigned short* bp0 = wfrag + (size_t)(kq * (KPER / 16)) * 2048 + lane * 8;

    for (int r = 0; r < NROUNDS; ++r) {
        #pragma unroll
        for (int nt = 0; nt < 4; ++nt) {
            const unsigned short* tp = bp0 + (size_t)(r * 4 + nt) * 2048;
            half8 bh0 = *(const half8*)(tp);
            half8 bh1 = *(const half8*)(tp + 512);
            half8 bl0 = *(const half8*)(tp + 1024);
            half8 bl1 = *(const half8*)(tp + 1536);
            f32x4 acc[2];
            #pragma unroll
            for (int mt = 0; mt < 2; ++mt) {
                f32x4 a = {0.f, 0.f, 0.f, 0.f};
                a = MFMA_F16(a_h[mt][0], bh0, a);
                a = MFMA_F16(a_h[mt][1], bh1, a);
                a = MFMA_F16(a_l[mt][0], bh0, a);
                a = MFMA_F16(a_l[mt][1], bh1, a);
                a = MFMA_F16(a_h[mt][0], bl0, a);
                a = MFMA_F16(a_h[mt][1], bl1, a);
                acc[mt] = a;
            }
            const int c = kq * KPER + r * 64 + nt * 16 + n_a;
            #pragma unroll
            for (int mt = 0; mt < 2; ++mt)
                #pragma unroll
                for (int i = 0; i < 4; ++i) {
                    float v = acc[mt][i];
                    m2v[mt][i] = __builtin_amdgcn_fmed3f(v, m1v[mt][i], m2v[mt][i]);
                    bool gt = v > m1v[mt][i];
                    kkv[mt][i] = gt ? c : kkv[mt][i];
                    m1v[mt][i] = fmaxf(m1v[mt][i], v);
                }
        }
    }

    // reduce top-2 across 16 col-lanes per row; write compressed partials
    #pragma unroll
    for (int mt = 0; mt < 2; ++mt)
        #pragma unroll
        for (int i = 0; i < 4; ++i) {
            float v1 = m1v[mt][i], v2 = m2v[mt][i];
            int k = kkv[mt][i];
            #pragma unroll
            for (int off = 1; off < 16; off <<= 1) {
                float o1 = __shfl_xor(v1, off);
                float o2 = __shfl_xor(v2, off);
                int ok = __shfl_xor(k, off);
                float lo = fminf(v1, o1);
                v2 = fmaxf(fmaxf(v2, o2), lo);
                bool take = (o1 > v1) || (o1 == v1 && ok < k);
                k = take ? ok : k;
                v1 = fmaxf(v1, o1);
            }
            if (n_a == 0) {
                int row_g = rowblk * 128 + wv * 32 + mt * 16 + quad * 4 + i;
                float gap = v1 - v2;
                unsigned gb = __float_as_uint(gap) >> 16;   // bf16-truncate: conservative
                pm1[row_g * 4 + kq] = v1;
                pack[row_g * 4 + kq] = (gb << 16) | (unsigned)k;
            }
        }
}

// ---------------- kernel C: merge 4 K-partials per row, flag close rows ----------------
__global__ void merge_kernel(const float* __restrict__ pm1, const unsigned int* __restrict__ pack,
                             int* __restrict__ idx_ws,
                             int* __restrict__ countp, int* __restrict__ list) {
    int row = blockIdx.x * blockDim.x + threadIdx.x;
    if (row >= N_ROWS) return;
    float v1 = -3.4e38f, v2 = -3.4e38f;
    int k1 = 0x7fffffff;
    #pragma unroll
    for (int kq = 0; kq < KSPLIT; ++kq) {
        float a1 = pm1[row * 4 + kq];
        unsigned p = pack[row * 4 + kq];
        int ak = (int)(p & 0xFFFFu);
        float a2 = a1 - b2f((unsigned short)(p >> 16));
        if (a1 > v1) { v2 = fmaxf(v1, a2); v1 = a1; k1 = ak; }
        else { v2 = fmaxf(v2, a1); if (a1 == v1 && ak < k1) k1 = ak; }
    }
    idx_ws[row] = k1;
    if (v1 - v2 < MARGIN_S) {
        int pos = atomicAdd(countp, 1);
        if (pos < LIST_CAP) list[pos] = row;
    }
}

// ---------------- kernel D: exact fp32 re-rank, parallel over (slot x code-chunk) ----------------
__launch_bounds__(256, 4)
__global__ void fallback_kernel(const float* __restrict__ zn, const float* __restrict__ wT,
                                const float* __restrict__ wsq,
                                const int* __restrict__ countp, const int* __restrict__ list,
                                float* __restrict__ fbmin, int* __restrict__ fbk) {
    __shared__ float zr_s[64];
    __shared__ float zsq_s;
    __shared__ float wmin_s[4];
    __shared__ int wk_s[4];

    const int t = threadIdx.x;
    const int lane = t & 63;
    const int wv = t >> 6;
    const int count = min(*countp, LIST_CAP);
    const int nunits = count * 8;

    for (int bi = blockIdx.x; bi < nunits; bi += gridDim.x) {
        const int slot = bi >> 3;
        const int chunk = bi & 7;
        const int row = list[slot];

        __syncthreads();
        if (t < 64) {
            float v = zn[(size_t)row * DIM + t];
            zr_s[t] = v;
            float q = v * v;
            #pragma unroll
            for (int off = 32; off > 0; off >>= 1) q += __shfl_xor(q, off);
            if (t == 0) zsq_s = q;
        }
        __syncthreads();

        float acc0 = 0.f, acc1 = 0.f, acc2 = 0.f, acc3 = 0.f;
        const float* wTp = wT + chunk * 1024 + t;
        #pragma unroll 8
        for (int d = 0; d < 64; ++d) {
            float zd = zr_s[d];
            const float* p = wTp + (size_t)d * KCODES;
            acc0 = fmaf(zd, p[0], acc0);
            acc1 = fmaf(zd, p[256], acc1);
            acc2 = fmaf(zd, p[512], acc2);
            acc3 = fmaf(zd, p[768], acc3);
        }

        float zq2 = zsq_s;
        float dmin = 3.4e38f;
        int kmin = 0;
        float a[4] = {acc0, acc1, acc2, acc3};
        #pragma unroll
        for (int j = 0; j < 4; ++j) {
            int c = chunk * 1024 + j * 256 + t;
            float dist = (zq2 - 2.0f * a[j]) + wsq[c];
            if (dist < dmin) { dmin = dist; kmin = c; }
        }
        #pragma unroll
        for (int off = 1; off < 64; off <<= 1) {
            float d2 = __shfl_xor(dmin, off);
            int k2 = __shfl_xor(kmin, off);
            if (d2 < dmin || (d2 == dmin && k2 < kmin)) { dmin = d2; kmin = k2; }
        }
        if (lane == 0) { wmin_s[wv] = dmin; wk_s[wv] = kmin; }
        __syncthreads();
        if (t == 0) {
            float dv = wmin_s[0]; int kv = wk_s[0];
            #pragma unroll
            for (int i = 1; i < 4; ++i) {
                float d2 = wmin_s[i]; int k2 = wk_s[i];
                if (d2 < dv || (d2 == dv && k2 < kv)) { dv = d2; kv = k2; }
            }
            fbmin[bi] = dv;
            fbk[bi] = kv;
        }
    }
}

// ---------------- kernel D2: merge 8 chunk partials per flagged row (+ zero esum) ----------------
__global__ void merge2_kernel(const float* __restrict__ fbmin, const int* __restrict__ fbk,
                              const int* __restrict__ countp, const int* __restrict__ list,
                              int* __restrict__ idx_ws, float* __restrict__ esum) {
    int gid = blockIdx.x * blockDim.x + threadIdx.x;
    float4 zero4 = {0.f, 0.f, 0.f, 0.f};
    *(float4*)(esum + (size_t)gid * 8) = zero4;
    *(float4*)(esum + (size_t)gid * 8 + 4) = zero4;
    int count = min(*countp, LIST_CAP);
    if (gid >= count) return;
    float dv = 3.4e38f;
    int kv = 0;
    #pragma unroll
    for (int c = 0; c < 8; ++c) {
        float d2 = fbmin[gid * 8 + c];
        int k2 = fbk[gid * 8 + c];
        if (d2 < dv || (d2 == dv && k2 < kv)) { dv = d2; kv = k2; }
    }
    idx_ws[list[gid]] = kv;
}

// ---------------- kernel E: gather z_q (over zn in-place), idx out, loss, EMA scatter ----------------
__global__ void stats_kernel(float* __restrict__ zq,              // holds zn on entry
                             const float* __restrict__ w,
                             const int* __restrict__ idx_ws,
                             float* __restrict__ idx_out,
                             float* __restrict__ bins,
                             float* __restrict__ esum,
                             float* __restrict__ loss_acc) {
    const int lane = threadIdx.x & 63;
    const int wv = threadIdx.x >> 6;
    const int gw = blockIdx.x * 4 + wv;
    const int nw = gridDim.x * 4;
    float lsum = 0.f;
    for (int row = gw; row < N_ROWS; row += nw) {
        float znv = zq[(size_t)row * DIM + lane];
        int k = idx_ws[row];
        float wq = w[(size_t)k * DIM + lane];
        zq[(size_t)row * DIM + lane] = wq;
        if (lane == 0) idx_out[row] = (float)k;
        float diff = wq - znv;
        lsum += diff * diff;
        atomicAdd(&esum[(size_t)k * DIM + lane], znv);
        if (lane == 0) atomicAdd(&bins[k], 1.0f);
    }
    __shared__ float red[256];
    red[threadIdx.x] = lsum;
    __syncthreads();
    for (int s = 128; s > 0; s >>= 1) {
        if (threadIdx.x < s) red[threadIdx.x] += red[threadIdx.x + s];
        __syncthreads();
    }
    if (threadIdx.x == 0) atomicAdd(loss_acc, red[0]);
}

// ---------------- kernel F: per-code EMA finalize + loss scalar ----------------
__global__ void finalize_kernel(const float* __restrict__ w,
                                const float* __restrict__ cs,
                                const float* __restrict__ ea,
                                const float* __restrict__ bins,
                                const float* __restrict__ esum,
                                const float* __restrict__ loss_acc,
                                float* __restrict__ out_cs,
                                float* __restrict__ out_ea,
                                float* __restrict__ out_w,
                                float* __restrict__ out_loss) {
    const int gid = blockIdx.x * blockDim.x + threadIdx.x;
    if (gid == 0) out_loss[0] = 0.25f * loss_acc[0] / 4194304.0f;
    const int k = gid >> 6;
    const int lane = threadIdx.x & 63;
    if (k >= KCODES) return;
    float b = bins[k];
    if (lane == 0) out_cs[k] = cs[k] * 0.99f + 0.01f * b;
    size_t off = (size_t)k * DIM + lane;
    float es = esum[off];
    out_ea[off] = ea[off] * 0.99f + 0.01f * es;
    float wv = w[off];
    float bc = (b == 0.0f) ? 1.0f : b;
    float t = es / bc;
    float s = t * t;
    #pragma unroll
    for (int o = 32; o > 0; o >>= 1) s += __shfl_xor(s, o);
    float en = t / fmaxf(sqrtf(s), 1e-12f);
    if (b == 0.0f) en = wv;
    float nw = wv * 0.99f + 0.01f * en;
    float s2 = nw * nw;
    #pragma unroll
    for (int o = 32; o > 0; o >>= 1) s2 += __shfl_xor(s2, o);
    out_w[off] = nw / fmaxf(sqrtf(s2), 1e-12f);
}

extern "C" void kernel_launch(void* const* d_in, const int* in_sizes, int n_in,
                              void* d_out, int out_size, void* d_ws, size_t ws_size,
                              hipStream_t stream) {
    const float* z  = (const float*)d_in[0];
    const float* w  = (const float*)d_in[1];
    const float* cs = (const float*)d_in[2];
    const float* ea = (const float*)d_in[3];

    float* out = (float*)d_out;
    float* out_zq   = out;                 // 4194304  (zn scratch)
    float* out_loss = out + 4194304;       // 1        (count scratch)
    float* out_idx  = out + 4194305;       // 65536    (list scratch)
    float* out_cs   = out + 4259841;       // 8192
    float* out_ea   = out + 4268033;       // 524288
    float* out_w    = out + 4792321;       // 524288   (pm1/fbmin + pack/fbk scratch)

    float*          zn     = out_zq;
    int*            countp = (int*)(out + 4194304);
    int*            list   = (int*)(out + 4194305);
    unsigned short* wfrag  = (unsigned short*)(out + 4268032);   // 16B-aligned, 2 MB
    float*          pm1    = out + 4792321;
    unsigned int*   pack   = (unsigned int*)(out + 5054465);
    float*          fbmin  = pm1;
    int*            fbk    = (int*)pack;

    float* ws = (float*)d_ws;
    float* wsq  = ws + WS_WSQ;
    int*   idxb = (int*)(ws + WS_IDX);
    float* bins = ws + WS_BINS;
    float* esum = ws + WS_ESUM;
    float* wT   = ws + WS_ESUM;            // wT lives here until merge2 zeroes it
    float* loss = ws + WS_LOSS;

    prep_z_kernel<<<N_ROWS / 64, 256, 0, stream>>>(z, zn, countp, loss);
    prep_w_kernel<<<KCODES / 64, 256, 0, stream>>>(w, wsq, wfrag, wT, bins);
    argmin_mfma_kernel<<<(N_ROWS / 128) * KSPLIT, 256, 0, stream>>>(zn, wfrag, pm1, pack);
    merge_kernel<<<N_ROWS / 256, 256, 0, stream>>>(pm1, pack, idxb, countp, list);
    fallback_kernel<<<2048, 256, 0, stream>>>(zn, wT, wsq, countp, list, fbmin, fbk);
    merge2_kernel<<<256, 256, 0, stream>>>(fbmin, fbk, countp, list, idxb, esum);
    stats_kernel<<<512, 256, 0, stream>>>(out_zq, w, idxb, out_idx, bins, esum, loss);
    finalize_kernel<<<KCODES * 64 / 256, 256, 0, stream>>>(w, cs, ea, bins, esum, loss,
                                                           out_cs, out_ea, out_w, out_loss);
}